// Round 20
// baseline (204.628 us; speedup 1.0000x reference)
//
#include <hip/hip_runtime.h>
#include <math.h>

#define NN 20000          // nodes
#define NE 320000         // edges (before self loops)
#define NT (NE + NN)      // with self loops
#define F 256             // features (HEADS*C)
#define NEG 0.2f

// k_prep block partition (256 threads each): cvtW x3 | edge count
#define CVTW_B (3 * F * F / 256)         // 768  : one element/thread
#define CNT_B  (NE / 256)                // 1250 : one edge/thread
#define PREP_B (CVTW_B + CNT_B)          // 2018

#define SCAN_B 20                        // 20 blocks x 1024 threads >= NN
#define GTILES ((NN + 31) / 32)          // 625 row-tiles for layer-1 gemm
#define FILL_B (NE / 256)                // 1250 fill blocks (appended to layer-1 gemm)
#define AGTILES (NN / 16)                // 1250 16-row tiles for fused agg+gemm

typedef _Float16 half8 __attribute__((ext_vector_type(8)));   // 16 B
typedef _Float16 half4 __attribute__((ext_vector_type(4)));   // 8 B
typedef __attribute__((ext_vector_type(4))) float f4;         // 4 fp32

static __device__ __forceinline__ float lrelu(float x) { return x > 0.f ? x : NEG * x; }

// ---------------- fused prep: cvtW x3 | edge count ----------------
__global__ __launch_bounds__(256) void k_prep(const float* __restrict__ W0,
                                              const float* __restrict__ W1,
                                              const float* __restrict__ W2,
                                              const int* __restrict__ dst,
                                              _Float16* __restrict__ Wt,
                                              int* __restrict__ counts) {
    int b = blockIdx.x, t = threadIdx.x;
    if (b < CVTW_B) {
        int i = b * 256 + t;                         // < 3*F*F
        int layer = i >> 16, t16 = i & 65535;
        const float* Wp = (layer == 0) ? W0 : ((layer == 1) ? W1 : W2);
        int k = t16 >> 8, n = t16 & 255;
        Wt[(size_t)layer * 65536 + n * 256 + k] = (_Float16)Wp[t16];
    } else {
        int e = (b - CVTW_B) * 256 + t;              // < NE
        atomicAdd(&counts[dst[e]], 1);
    }
}

// ---------------- multi-block scan (A: local scan, B: add base + emit) ----------------
__global__ __launch_bounds__(1024) void k_scanA(const int* __restrict__ counts,
                                                int* __restrict__ offs, int* __restrict__ bsum) {
    int t = threadIdx.x;
    int i = blockIdx.x * 1024 + t;
    int v = (i < NN) ? counts[i] + 1 : 0;            // +1 = self loop
    __shared__ int sm[1024];
    sm[t] = v;
    __syncthreads();
    for (int o = 1; o < 1024; o <<= 1) {
        int u = (t >= o) ? sm[t - o] : 0;
        __syncthreads();
        sm[t] += u;
        __syncthreads();
    }
    if (i < NN) offs[i] = sm[t] - v;                 // local exclusive
    if (t == 1023) bsum[blockIdx.x] = sm[t];         // block total
}

__global__ __launch_bounds__(1024) void k_scanB(int* __restrict__ offs, const int* __restrict__ bsum,
                                                int* __restrict__ esrc, int* __restrict__ cursor) {
    int t = threadIdx.x;
    int b = blockIdx.x;
    __shared__ int base_sm;
    if (t == 0) {
        int s = 0;
        for (int j = 0; j < b; j++) s += bsum[j];
        base_sm = s;
    }
    __syncthreads();
    int base = base_sm;
    int i = b * 1024 + t;
    if (i < NN) {
        int o = offs[i] + base;
        offs[i] = o;
        esrc[o] = i;                                 // self loop in slot 0
        cursor[i] = o + 1;                           // cursor for edge fill (aliases counts)
    }
    if (b == SCAN_B - 1 && t == 1023) offs[NN] = base + bsum[b];
}

// ---------------- layer-1 MFMA GEMM (fp32 A in-register cvt) + fused edge fill ----------------
__global__ __launch_bounds__(256) void k_gemm1(
        const float* __restrict__ X32, const _Float16* __restrict__ Wt,
        const float* __restrict__ As, const float* __restrict__ Ad,
        _Float16* __restrict__ H, float* __restrict__ S,
        const int* __restrict__ src, const int* __restrict__ dst,
        int* __restrict__ cursor, int* __restrict__ esrc) {
    int rb = blockIdx.x;
    int t = threadIdx.x;
    if (rb >= GTILES) {                              // fused edge fill
        int e = (rb - GTILES) * 256 + t;             // exact: 1250*256 == NE
        int p = atomicAdd(&cursor[dst[e]], 1);
        esrc[p] = src[e];
        return;
    }

    int head = t >> 6, lane = t & 63;
    int lr = lane & 15, lg = lane >> 4;
    int row0 = rb * 32;
    int col0 = head * 64;

    int offA[2], offB[4];
    #pragma unroll
    for (int m = 0; m < 2; m++) offA[m] = (row0 + m * 16 + lr) * F + lg * 8;
    #pragma unroll
    for (int n = 0; n < 4; n++) offB[n] = (col0 + n * 16 + lr) * F + lg * 8;

    auto loadA = [&](int m, int k0) -> half8 {
        const float4* p4 = (const float4*)&X32[offA[m] + k0];
        float4 u = p4[0], v = p4[1];
        half8 h;
        h[0] = (_Float16)u.x; h[1] = (_Float16)u.y;
        h[2] = (_Float16)u.z; h[3] = (_Float16)u.w;
        h[4] = (_Float16)v.x; h[5] = (_Float16)v.y;
        h[6] = (_Float16)v.z; h[7] = (_Float16)v.w;
        return h;
    };

    half8 aa[2][2], bb[2][4];
    #pragma unroll
    for (int m = 0; m < 2; m++) aa[0][m] = loadA(m, 0);
    #pragma unroll
    for (int n = 0; n < 4; n++) bb[0][n] = *(const half8*)&Wt[offB[n]];

    f4 acc[2][4] = {};
    #pragma unroll
    for (int it = 0; it < 8; it++) {
        const int cur = it & 1, nxt = cur ^ 1;
        if (it < 7) {
            int k0 = (it + 1) * 32;
            #pragma unroll
            for (int m = 0; m < 2; m++) aa[nxt][m] = loadA(m, k0);
            #pragma unroll
            for (int n = 0; n < 4; n++) bb[nxt][n] = *(const half8*)&Wt[offB[n] + k0];
        }
        #pragma unroll
        for (int m = 0; m < 2; m++)
            #pragma unroll
            for (int n = 0; n < 4; n++)
                acc[m][n] = __builtin_amdgcn_mfma_f32_16x16x32_f16(aa[cur][m], bb[cur][n], acc[m][n], 0, 0, 0);
    }

    float as_r[4], ad_r[4];
    #pragma unroll
    for (int n = 0; n < 4; n++) {
        as_r[n] = As[head * 64 + n * 16 + lr];
        ad_r[n] = Ad[head * 64 + n * 16 + lr];
    }

    #pragma unroll
    for (int m = 0; m < 2; m++) {
        #pragma unroll
        for (int j = 0; j < 4; j++) {
            int rr = row0 + m * 16 + lg * 4 + j;
            float ssum = 0.f, dsum = 0.f;
            #pragma unroll
            for (int n = 0; n < 4; n++) {
                float v = acc[m][n][j];
                H[(size_t)rr * F + col0 + n * 16 + lr] = (_Float16)v;
                ssum = fmaf(v, as_r[n], ssum);
                dsum = fmaf(v, ad_r[n], dsum);
            }
            #pragma unroll
            for (int o = 1; o < 16; o <<= 1) {
                ssum += __shfl_xor(ssum, o, 64);
                dsum += __shfl_xor(dsum, o, 64);
            }
            if (lr == 0) {
                S[rr * 8 + head] = ssum;
                S[rr * 8 + 4 + head] = dsum;
            }
        }
    }
}

// ---------------- fused agg(layer l) + gemm(layer l+1), per 16-row tile ----------------
// 256 threads (4 waves), grid 1250, up to 8 blocks/CU. Agg: wave w aggs nodes
// row0+4w..+3 with a 16-edge-deep (8-pair) gather pipeline -> ~2x outstanding
// loads per CU vs 8-deep (the fused grid has 1/4 the blocks of standalone agg,
// so per-wave depth must compensate). Gemm: wave w = head w, 16x64 sub-tile.
__global__ __launch_bounds__(256, 8) void k_aggemm(
        const _Float16* __restrict__ Hin, const float* __restrict__ Sin,
        const int* __restrict__ offs, const int* __restrict__ esrc,
        const float* __restrict__ bias,                  // layer l
        const _Float16* __restrict__ Wt,                 // layer l+1 (transposed)
        const float* __restrict__ As, const float* __restrict__ Ad,   // layer l+1
        _Float16* __restrict__ Hout, float* __restrict__ Sout) {
    __shared__ _Float16 xs[16][264];                 // +8 fp16 pad per row
    int rb = blockIdx.x;
    int w = threadIdx.x >> 6, l = threadIdx.x & 63;
    int half = l >> 5, j = l & 31, hh = j >> 3;
    int row0 = rb * 16;

    float4 ba = ((const float4*)bias)[2 * j];
    float4 bb2 = ((const float4*)bias)[2 * j + 1];

    // ---- agg phase: 4 nodes per wave, 16-edge-deep pipeline ----
    for (int r = 0; r < 4; r++) {
        int node = row0 + w * 4 + r;
        int p0 = offs[node], p1 = offs[node + 1];
        float sdst = Sin[node * 8 + 4 + hh];

        float a0 = 0.f, a1 = 0.f, a2 = 0.f, a3 = 0.f;
        float a4 = 0.f, a5 = 0.f, a6 = 0.f, a7 = 0.f;
        float d = 0.f;
        int p = p0;
        for (; p + 16 <= p1; p += 16) {              // 8 pairs = 16 edges in flight
            int sn[8];
            #pragma unroll
            for (int i = 0; i < 8; i++) sn[i] = esrc[p + 2 * i + half];
            half8 hv[8];
            #pragma unroll
            for (int i = 0; i < 8; i++) hv[i] = *(const half8*)&Hin[(size_t)sn[i] * F + j * 8];
            float wgt[8];
            #pragma unroll
            for (int i = 0; i < 8; i++)
                wgt[i] = __expf(fminf(lrelu(Sin[sn[i] * 8 + hh] + sdst), 60.f));
            #pragma unroll
            for (int i = 0; i < 8; i++) {
                d += wgt[i];
                a0 = fmaf(wgt[i], (float)hv[i][0], a0);
                a1 = fmaf(wgt[i], (float)hv[i][1], a1);
                a2 = fmaf(wgt[i], (float)hv[i][2], a2);
                a3 = fmaf(wgt[i], (float)hv[i][3], a3);
                a4 = fmaf(wgt[i], (float)hv[i][4], a4);
                a5 = fmaf(wgt[i], (float)hv[i][5], a5);
                a6 = fmaf(wgt[i], (float)hv[i][6], a6);
                a7 = fmaf(wgt[i], (float)hv[i][7], a7);
            }
        }
        for (; p + 8 <= p1; p += 8) {                // 4 pairs = 8 edges
            int sn[4];
            #pragma unroll
            for (int i = 0; i < 4; i++) sn[i] = esrc[p + 2 * i + half];
            half8 hv[4];
            #pragma unroll
            for (int i = 0; i < 4; i++) hv[i] = *(const half8*)&Hin[(size_t)sn[i] * F + j * 8];
            float wgt[4];
            #pragma unroll
            for (int i = 0; i < 4; i++)
                wgt[i] = __expf(fminf(lrelu(Sin[sn[i] * 8 + hh] + sdst), 60.f));
            #pragma unroll
            for (int i = 0; i < 4; i++) {
                d += wgt[i];
                a0 = fmaf(wgt[i], (float)hv[i][0], a0);
                a1 = fmaf(wgt[i], (float)hv[i][1], a1);
                a2 = fmaf(wgt[i], (float)hv[i][2], a2);
                a3 = fmaf(wgt[i], (float)hv[i][3], a3);
                a4 = fmaf(wgt[i], (float)hv[i][4], a4);
                a5 = fmaf(wgt[i], (float)hv[i][5], a5);
                a6 = fmaf(wgt[i], (float)hv[i][6], a6);
                a7 = fmaf(wgt[i], (float)hv[i][7], a7);
            }
        }
        for (; p + 2 <= p1; p += 2) {
            int sn = esrc[p + half];
            half8 hv = *(const half8*)&Hin[(size_t)sn * F + j * 8];
            float wgt = __expf(fminf(lrelu(Sin[sn * 8 + hh] + sdst), 60.f));
            d += wgt;
            a0 = fmaf(wgt, (float)hv[0], a0);
            a1 = fmaf(wgt, (float)hv[1], a1);
            a2 = fmaf(wgt, (float)hv[2], a2);
            a3 = fmaf(wgt, (float)hv[3], a3);
            a4 = fmaf(wgt, (float)hv[4], a4);
            a5 = fmaf(wgt, (float)hv[5], a5);
            a6 = fmaf(wgt, (float)hv[6], a6);
            a7 = fmaf(wgt, (float)hv[7], a7);
        }
        if (p < p1) {                                // odd tail: half==1 lanes contribute 0
            int sn = esrc[p];
            half8 hv = *(const half8*)&Hin[(size_t)sn * F + j * 8];
            float wgt = (half == 0) ? __expf(fminf(lrelu(Sin[sn * 8 + hh] + sdst), 60.f)) : 0.f;
            d += wgt;
            a0 = fmaf(wgt, (float)hv[0], a0);
            a1 = fmaf(wgt, (float)hv[1], a1);
            a2 = fmaf(wgt, (float)hv[2], a2);
            a3 = fmaf(wgt, (float)hv[3], a3);
            a4 = fmaf(wgt, (float)hv[4], a4);
            a5 = fmaf(wgt, (float)hv[5], a5);
            a6 = fmaf(wgt, (float)hv[6], a6);
            a7 = fmaf(wgt, (float)hv[7], a7);
        }

        d  += __shfl_xor(d, 32, 64);
        a0 += __shfl_xor(a0, 32, 64);
        a1 += __shfl_xor(a1, 32, 64);
        a2 += __shfl_xor(a2, 32, 64);
        a3 += __shfl_xor(a3, 32, 64);
        a4 += __shfl_xor(a4, 32, 64);
        a5 += __shfl_xor(a5, 32, 64);
        a6 += __shfl_xor(a6, 32, 64);
        a7 += __shfl_xor(a7, 32, 64);

        float inv = 1.f / d;
        if (half == 0) {
            half8 o;
            o[0] = (_Float16)fmaxf(fmaf(a0, inv, ba.x), 0.f);
            o[1] = (_Float16)fmaxf(fmaf(a1, inv, ba.y), 0.f);
            o[2] = (_Float16)fmaxf(fmaf(a2, inv, ba.z), 0.f);
            o[3] = (_Float16)fmaxf(fmaf(a3, inv, ba.w), 0.f);
            o[4] = (_Float16)fmaxf(fmaf(a4, inv, bb2.x), 0.f);
            o[5] = (_Float16)fmaxf(fmaf(a5, inv, bb2.y), 0.f);
            o[6] = (_Float16)fmaxf(fmaf(a6, inv, bb2.z), 0.f);
            o[7] = (_Float16)fmaxf(fmaf(a7, inv, bb2.w), 0.f);
            *(half8*)&xs[w * 4 + r][j * 8] = o;
        }
    }
    __syncthreads();

    // ---- gemm phase: wave w = head w, 16x64 sub-tile, A from LDS ----
    int head = w;
    int lr = l & 15, lg = l >> 4;
    int col0 = head * 64;

    int offB[4];
    #pragma unroll
    for (int n = 0; n < 4; n++) offB[n] = (col0 + n * 16 + lr) * F + lg * 8;

    half8 aa[2], bbf[2][4];
    aa[0] = *(const half8*)&xs[lr][lg * 8];
    #pragma unroll
    for (int n = 0; n < 4; n++) bbf[0][n] = *(const half8*)&Wt[offB[n]];

    f4 acc[4] = {};
    #pragma unroll
    for (int it = 0; it < 8; it++) {
        const int cur = it & 1, nxt = cur ^ 1;
        if (it < 7) {
            int k0 = (it + 1) * 32;
            aa[nxt] = *(const half8*)&xs[lr][lg * 8 + k0];
            #pragma unroll
            for (int n = 0; n < 4; n++) bbf[nxt][n] = *(const half8*)&Wt[offB[n] + k0];
        }
        #pragma unroll
        for (int n = 0; n < 4; n++)
            acc[n] = __builtin_amdgcn_mfma_f32_16x16x32_f16(aa[cur], bbf[cur][n], acc[n], 0, 0, 0);
    }

    float as_r[4], ad_r[4];
    #pragma unroll
    for (int n = 0; n < 4; n++) {
        as_r[n] = As[head * 64 + n * 16 + lr];
        ad_r[n] = Ad[head * 64 + n * 16 + lr];
    }

    #pragma unroll
    for (int j2 = 0; j2 < 4; j2++) {
        int rr = row0 + lg * 4 + j2;
        float ssum = 0.f, dsum = 0.f;
        #pragma unroll
        for (int n = 0; n < 4; n++) {
            float v = acc[n][j2];
            Hout[(size_t)rr * F + col0 + n * 16 + lr] = (_Float16)v;
            ssum = fmaf(v, as_r[n], ssum);
            dsum = fmaf(v, ad_r[n], dsum);
        }
        #pragma unroll
        for (int o = 1; o < 16; o <<= 1) {
            ssum += __shfl_xor(ssum, o, 64);
            dsum += __shfl_xor(dsum, o, 64);
        }
        if (lr == 0) {
            Sout[rr * 8 + head] = ssum;
            Sout[rr * 8 + 4 + head] = dsum;
        }
    }
}

// ---------------- final softmax aggregation + bias + L2-normalize ----------------
__global__ __launch_bounds__(256) void k_aggF(const _Float16* __restrict__ Hm, const float* __restrict__ S,
                                              const int* __restrict__ offs, const int* __restrict__ esrc,
                                              const float* __restrict__ bias,
                                              float* __restrict__ ofp) {
    int node = blockIdx.x * 4 + (threadIdx.x >> 6);
    if (node >= NN) return;
    int l = threadIdx.x & 63;
    int half = l >> 5;
    int j = l & 31;
    int hh = j >> 3;

    int p0 = offs[node], p1 = offs[node + 1];
    float sdst = S[node * 8 + 4 + hh];

    float a0 = 0.f, a1 = 0.f, a2 = 0.f, a3 = 0.f;
    float a4 = 0.f, a5 = 0.f, a6 = 0.f, a7 = 0.f;
    float d = 0.f;
    int p = p0;
    for (; p + 8 <= p1; p += 8) {
        int sn[4];
        #pragma unroll
        for (int i = 0; i < 4; i++) sn[i] = esrc[p + 2 * i + half];
        half8 hv[4];
        #pragma unroll
        for (int i = 0; i < 4; i++) hv[i] = *(const half8*)&Hm[(size_t)sn[i] * F + j * 8];
        float wgt[4];
        #pragma unroll
        for (int i = 0; i < 4; i++)
            wgt[i] = __expf(fminf(lrelu(S[sn[i] * 8 + hh] + sdst), 60.f));
        #pragma unroll
        for (int i = 0; i < 4; i++) {
            d += wgt[i];
            a0 = fmaf(wgt[i], (float)hv[i][0], a0);
            a1 = fmaf(wgt[i], (float)hv[i][1], a1);
            a2 = fmaf(wgt[i], (float)hv[i][2], a2);
            a3 = fmaf(wgt[i], (float)hv[i][3], a3);
            a4 = fmaf(wgt[i], (float)hv[i][4], a4);
            a5 = fmaf(wgt[i], (float)hv[i][5], a5);
            a6 = fmaf(wgt[i], (float)hv[i][6], a6);
            a7 = fmaf(wgt[i], (float)hv[i][7], a7);
        }
    }
    for (; p + 2 <= p1; p += 2) {
        int sn = esrc[p + half];
        half8 hv = *(const half8*)&Hm[(size_t)sn * F + j * 8];
        float wgt = __expf(fminf(lrelu(S[sn * 8 + hh] + sdst), 60.f));
        d += wgt;
        a0 = fmaf(wgt, (float)hv[0], a0);
        a1 = fmaf(wgt, (float)hv[1], a1);
        a2 = fmaf(wgt, (float)hv[2], a2);
        a3 = fmaf(wgt, (float)hv[3], a3);
        a4 = fmaf(wgt, (float)hv[4], a4);
        a5 = fmaf(wgt, (float)hv[5], a5);
        a6 = fmaf(wgt, (float)hv[6], a6);
        a7 = fmaf(wgt, (float)hv[7], a7);
    }
    if (p < p1) {
        int sn = esrc[p];
        half8 hv = *(const half8*)&Hm[(size_t)sn * F + j * 8];
        float wgt = (half == 0) ? __expf(fminf(lrelu(S[sn * 8 + hh] + sdst), 60.f)) : 0.f;
        d += wgt;
        a0 = fmaf(wgt, (float)hv[0], a0);
        a1 = fmaf(wgt, (float)hv[1], a1);
        a2 = fmaf(wgt, (float)hv[2], a2);
        a3 = fmaf(wgt, (float)hv[3], a3);
        a4 = fmaf(wgt, (float)hv[4], a4);
        a5 = fmaf(wgt, (float)hv[5], a5);
        a6 = fmaf(wgt, (float)hv[6], a6);
        a7 = fmaf(wgt, (float)hv[7], a7);
    }

    d  += __shfl_xor(d, 32, 64);
    a0 += __shfl_xor(a0, 32, 64);
    a1 += __shfl_xor(a1, 32, 64);
    a2 += __shfl_xor(a2, 32, 64);
    a3 += __shfl_xor(a3, 32, 64);
    a4 += __shfl_xor(a4, 32, 64);
    a5 += __shfl_xor(a5, 32, 64);
    a6 += __shfl_xor(a6, 32, 64);
    a7 += __shfl_xor(a7, 32, 64);

    float inv = 1.f / d;
    float4 ba = ((const float4*)bias)[2 * j];
    float4 bb = ((const float4*)bias)[2 * j + 1];
    float r0 = fmaf(a0, inv, ba.x);
    float r1 = fmaf(a1, inv, ba.y);
    float r2 = fmaf(a2, inv, ba.z);
    float r3 = fmaf(a3, inv, ba.w);
    float r4 = fmaf(a4, inv, bb.x);
    float r5 = fmaf(a5, inv, bb.y);
    float r6 = fmaf(a6, inv, bb.z);
    float r7 = fmaf(a7, inv, bb.w);

    float ss = r0 * r0 + r1 * r1 + r2 * r2 + r3 * r3
             + r4 * r4 + r5 * r5 + r6 * r6 + r7 * r7;
    #pragma unroll
    for (int o = 1; o < 32; o <<= 1) ss += __shfl_xor(ss, o, 64);
    float nrm = 1.f / fmaxf(sqrtf(ss), 1e-12f);
    if (half == 0) {
        ((float4*)ofp)[(size_t)node * 64 + 2 * j] =
            make_float4(r0 * nrm, r1 * nrm, r2 * nrm, r3 * nrm);
        ((float4*)ofp)[(size_t)node * 64 + 2 * j + 1] =
            make_float4(r4 * nrm, r5 * nrm, r6 * nrm, r7 * nrm);
    }
}

extern "C" void kernel_launch(void* const* d_in, const int* in_sizes, int n_in,
                              void* d_out, int out_size, void* d_ws, size_t ws_size,
                              hipStream_t stream) {
    const float* x = (const float*)d_in[0];
    const int* ei = (const int*)d_in[1];
    const int* src = ei;            // edge_index[0]
    const int* dst = ei + NE;       // edge_index[1]
    const float* W[3]  = {(const float*)d_in[2],  (const float*)d_in[6],  (const float*)d_in[10]};
    const float* As[3] = {(const float*)d_in[3],  (const float*)d_in[7],  (const float*)d_in[11]};
    const float* Ad[3] = {(const float*)d_in[4],  (const float*)d_in[8],  (const float*)d_in[12]};
    const float* Bs[3] = {(const float*)d_in[5],  (const float*)d_in[9],  (const float*)d_in[13]};
    float* out = (float*)d_out;

    // workspace carve (all 16B aligned); H/S double-buffered across layers
    char* w = (char*)d_ws;
    _Float16* H_A = (_Float16*)w;            w += (size_t)NN * F * 2;        // 10.24 MB
    _Float16* H_B = (_Float16*)w;            w += (size_t)NN * F * 2;        // 10.24 MB
    float* S_A = (float*)w;                  w += (size_t)NN * 8 * 4;        // 0.64 MB
    float* S_B = (float*)w;                  w += (size_t)NN * 8 * 4;        // 0.64 MB
    _Float16* Wt = (_Float16*)w;             w += (size_t)3 * F * F * 2;     // 0.39 MB
    int* counts = (int*)w;                   w += (size_t)NN * 4;            // cursor after scan
    int* offs = (int*)w;                     w += (size_t)(NN + 4) * 4;
    int* bsum = (int*)w;                     w += (size_t)32 * 4;
    int* esrc = (int*)w;

    hipMemsetAsync(counts, 0, (size_t)NN * 4, stream);
    k_prep<<<PREP_B, 256, 0, stream>>>(W[0], W[1], W[2], dst, Wt, counts);
    k_scanA<<<SCAN_B, 1024, 0, stream>>>(counts, offs, bsum);
    k_scanB<<<SCAN_B, 1024, 0, stream>>>(offs, bsum, esrc, counts);

    // layer 1 gemm (+edge fill) -> H_A,S_A
    k_gemm1<<<GTILES + FILL_B, 256, 0, stream>>>(x, Wt, As[0], Ad[0], H_A, S_A,
                                                 src, dst, counts, esrc);
    // agg1 + gemm2 -> H_B,S_B
    k_aggemm<<<AGTILES, 256, 0, stream>>>(H_A, S_A, offs, esrc, Bs[0],
                                          Wt + 65536, As[1], Ad[1], H_B, S_B);
    // agg2 + gemm3 -> H_A,S_A
    k_aggemm<<<AGTILES, 256, 0, stream>>>(H_B, S_B, offs, esrc, Bs[1],
                                          Wt + 2 * 65536, As[2], Ad[2], H_A, S_A);
    // agg3 + bias + L2-normalize -> out
    k_aggF<<<(NN + 3) / 4, 256, 0, stream>>>(H_A, S_A, offs, esrc, Bs[2], out);
}

// Round 21
// 181.851 us; speedup vs baseline: 1.1253x; 1.1253x over previous
//
#include <hip/hip_runtime.h>
#include <math.h>

#define NN 20000          // nodes
#define NE 320000         // edges (before self loops)
#define NT (NE + NN)      // with self loops
#define F 256             // features (HEADS*C)
#define NEG 0.2f

// k_prep block partition (256 threads each): cvtW x3 | edge count
#define CVTW_B (3 * F * F / 256)         // 768  : one element/thread
#define CNT_B  (NE / 256)                // 1250 : one edge/thread
#define PREP_B (CVTW_B + CNT_B)          // 2018

#define SCAN_B 20                        // 20 blocks x 1024 threads >= NN
#define GTILES ((NN + 31) / 32)          // 625 row-tiles for layer-1 gemm
#define FILL_B (NE / 256)                // 1250 fill blocks (appended to layer-1 gemm)
#define AGTILES (NN / 16)                // 1250 16-row tiles for fused agg+gemm

typedef _Float16 half8 __attribute__((ext_vector_type(8)));   // 16 B
typedef _Float16 half4 __attribute__((ext_vector_type(4)));   // 8 B
typedef __attribute__((ext_vector_type(4))) float f4;         // 4 fp32

static __device__ __forceinline__ float lrelu(float x) { return x > 0.f ? x : NEG * x; }

// ---------------- fused prep: cvtW x3 | edge count ----------------
__global__ __launch_bounds__(256) void k_prep(const float* __restrict__ W0,
                                              const float* __restrict__ W1,
                                              const float* __restrict__ W2,
                                              const int* __restrict__ dst,
                                              _Float16* __restrict__ Wt,
                                              int* __restrict__ counts) {
    int b = blockIdx.x, t = threadIdx.x;
    if (b < CVTW_B) {
        int i = b * 256 + t;                         // < 3*F*F
        int layer = i >> 16, t16 = i & 65535;
        const float* Wp = (layer == 0) ? W0 : ((layer == 1) ? W1 : W2);
        int k = t16 >> 8, n = t16 & 255;
        Wt[(size_t)layer * 65536 + n * 256 + k] = (_Float16)Wp[t16];
    } else {
        int e = (b - CVTW_B) * 256 + t;              // < NE
        atomicAdd(&counts[dst[e]], 1);
    }
}

// ---------------- multi-block scan (A: local scan, B: add base + emit) ----------------
__global__ __launch_bounds__(1024) void k_scanA(const int* __restrict__ counts,
                                                int* __restrict__ offs, int* __restrict__ bsum) {
    int t = threadIdx.x;
    int i = blockIdx.x * 1024 + t;
    int v = (i < NN) ? counts[i] + 1 : 0;            // +1 = self loop
    __shared__ int sm[1024];
    sm[t] = v;
    __syncthreads();
    for (int o = 1; o < 1024; o <<= 1) {
        int u = (t >= o) ? sm[t - o] : 0;
        __syncthreads();
        sm[t] += u;
        __syncthreads();
    }
    if (i < NN) offs[i] = sm[t] - v;                 // local exclusive
    if (t == 1023) bsum[blockIdx.x] = sm[t];         // block total
}

__global__ __launch_bounds__(1024) void k_scanB(int* __restrict__ offs, const int* __restrict__ bsum,
                                                int* __restrict__ esrc, int* __restrict__ cursor) {
    int t = threadIdx.x;
    int b = blockIdx.x;
    __shared__ int base_sm;
    if (t == 0) {
        int s = 0;
        for (int j = 0; j < b; j++) s += bsum[j];
        base_sm = s;
    }
    __syncthreads();
    int base = base_sm;
    int i = b * 1024 + t;
    if (i < NN) {
        int o = offs[i] + base;
        offs[i] = o;
        esrc[o] = i;                                 // self loop in slot 0
        cursor[i] = o + 1;                           // cursor for edge fill (aliases counts)
    }
    if (b == SCAN_B - 1 && t == 1023) offs[NN] = base + bsum[b];
}

// ---------------- layer-1 MFMA GEMM (fp32 A in-register cvt) + fused edge fill ----------------
__global__ __launch_bounds__(256) void k_gemm1(
        const float* __restrict__ X32, const _Float16* __restrict__ Wt,
        const float* __restrict__ As, const float* __restrict__ Ad,
        _Float16* __restrict__ H, float* __restrict__ S,
        const int* __restrict__ src, const int* __restrict__ dst,
        int* __restrict__ cursor, int* __restrict__ esrc) {
    int rb = blockIdx.x;
    int t = threadIdx.x;
    if (rb >= GTILES) {                              // fused edge fill
        int e = (rb - GTILES) * 256 + t;             // exact: 1250*256 == NE
        int p = atomicAdd(&cursor[dst[e]], 1);
        esrc[p] = src[e];
        return;
    }

    int head = t >> 6, lane = t & 63;
    int lr = lane & 15, lg = lane >> 4;
    int row0 = rb * 32;
    int col0 = head * 64;

    int offA[2], offB[4];
    #pragma unroll
    for (int m = 0; m < 2; m++) offA[m] = (row0 + m * 16 + lr) * F + lg * 8;
    #pragma unroll
    for (int n = 0; n < 4; n++) offB[n] = (col0 + n * 16 + lr) * F + lg * 8;

    auto loadA = [&](int m, int k0) -> half8 {
        const float4* p4 = (const float4*)&X32[offA[m] + k0];
        float4 u = p4[0], v = p4[1];
        half8 h;
        h[0] = (_Float16)u.x; h[1] = (_Float16)u.y;
        h[2] = (_Float16)u.z; h[3] = (_Float16)u.w;
        h[4] = (_Float16)v.x; h[5] = (_Float16)v.y;
        h[6] = (_Float16)v.z; h[7] = (_Float16)v.w;
        return h;
    };

    half8 aa[2][2], bb[2][4];
    #pragma unroll
    for (int m = 0; m < 2; m++) aa[0][m] = loadA(m, 0);
    #pragma unroll
    for (int n = 0; n < 4; n++) bb[0][n] = *(const half8*)&Wt[offB[n]];

    f4 acc[2][4] = {};
    #pragma unroll
    for (int it = 0; it < 8; it++) {
        const int cur = it & 1, nxt = cur ^ 1;
        if (it < 7) {
            int k0 = (it + 1) * 32;
            #pragma unroll
            for (int m = 0; m < 2; m++) aa[nxt][m] = loadA(m, k0);
            #pragma unroll
            for (int n = 0; n < 4; n++) bb[nxt][n] = *(const half8*)&Wt[offB[n] + k0];
        }
        #pragma unroll
        for (int m = 0; m < 2; m++)
            #pragma unroll
            for (int n = 0; n < 4; n++)
                acc[m][n] = __builtin_amdgcn_mfma_f32_16x16x32_f16(aa[cur][m], bb[cur][n], acc[m][n], 0, 0, 0);
    }

    float as_r[4], ad_r[4];
    #pragma unroll
    for (int n = 0; n < 4; n++) {
        as_r[n] = As[head * 64 + n * 16 + lr];
        ad_r[n] = Ad[head * 64 + n * 16 + lr];
    }

    #pragma unroll
    for (int m = 0; m < 2; m++) {
        #pragma unroll
        for (int j = 0; j < 4; j++) {
            int rr = row0 + m * 16 + lg * 4 + j;
            float ssum = 0.f, dsum = 0.f;
            #pragma unroll
            for (int n = 0; n < 4; n++) {
                float v = acc[m][n][j];
                H[(size_t)rr * F + col0 + n * 16 + lr] = (_Float16)v;
                ssum = fmaf(v, as_r[n], ssum);
                dsum = fmaf(v, ad_r[n], dsum);
            }
            #pragma unroll
            for (int o = 1; o < 16; o <<= 1) {
                ssum += __shfl_xor(ssum, o, 64);
                dsum += __shfl_xor(dsum, o, 64);
            }
            if (lr == 0) {
                S[rr * 8 + head] = ssum;
                S[rr * 8 + 4 + head] = dsum;
            }
        }
    }
}

// ---------------- fused agg(layer l) + gemm(layer l+1), per 16-row tile ----------------
// MEASURED-BEST CONFIG (R17, 182.6us): 512 threads (8 waves), grid 1250.
// Agg: wave w aggs nodes row0+2w, row0+2w+1 with the 8-edge-deep (4-pair) pipeline
// (16-deep tested twice: L2-thrash, FETCH +42%, regression). Gemm: wave w =
// (head w>>1, col-half w&1) 16x32 sub-tile; col-halves combine score partials via LDS.
__global__ __launch_bounds__(512, 4) void k_aggemm(
        const _Float16* __restrict__ Hin, const float* __restrict__ Sin,
        const int* __restrict__ offs, const int* __restrict__ esrc,
        const float* __restrict__ bias,                  // layer l
        const _Float16* __restrict__ Wt,                 // layer l+1 (transposed)
        const float* __restrict__ As, const float* __restrict__ Ad,   // layer l+1
        _Float16* __restrict__ Hout, float* __restrict__ Sout) {
    __shared__ _Float16 xs[16][264];                 // +8 fp16 pad per row
    __shared__ float sm_s[8][16], sm_d[8][16];       // per-wave partial score sums
    int rb = blockIdx.x;
    int w = threadIdx.x >> 6, l = threadIdx.x & 63;
    int half = l >> 5, j = l & 31, hh = j >> 3;
    int row0 = rb * 16;

    float4 ba = ((const float4*)bias)[2 * j];
    float4 bb2 = ((const float4*)bias)[2 * j + 1];

    // ---- agg phase: 2 nodes per wave, 8-edge-deep pipeline ----
    for (int r = 0; r < 2; r++) {
        int node = row0 + w * 2 + r;
        int p0 = offs[node], p1 = offs[node + 1];
        float sdst = Sin[node * 8 + 4 + hh];

        float a0 = 0.f, a1 = 0.f, a2 = 0.f, a3 = 0.f;
        float a4 = 0.f, a5 = 0.f, a6 = 0.f, a7 = 0.f;
        float d = 0.f;
        int p = p0;
        for (; p + 8 <= p1; p += 8) {                // 4 pairs = 8 edges in flight
            int sn[4];
            #pragma unroll
            for (int i = 0; i < 4; i++) sn[i] = esrc[p + 2 * i + half];
            half8 hv[4];
            #pragma unroll
            for (int i = 0; i < 4; i++) hv[i] = *(const half8*)&Hin[(size_t)sn[i] * F + j * 8];
            float wgt[4];
            #pragma unroll
            for (int i = 0; i < 4; i++)
                wgt[i] = __expf(fminf(lrelu(Sin[sn[i] * 8 + hh] + sdst), 60.f));
            #pragma unroll
            for (int i = 0; i < 4; i++) {
                d += wgt[i];
                a0 = fmaf(wgt[i], (float)hv[i][0], a0);
                a1 = fmaf(wgt[i], (float)hv[i][1], a1);
                a2 = fmaf(wgt[i], (float)hv[i][2], a2);
                a3 = fmaf(wgt[i], (float)hv[i][3], a3);
                a4 = fmaf(wgt[i], (float)hv[i][4], a4);
                a5 = fmaf(wgt[i], (float)hv[i][5], a5);
                a6 = fmaf(wgt[i], (float)hv[i][6], a6);
                a7 = fmaf(wgt[i], (float)hv[i][7], a7);
            }
        }
        for (; p + 2 <= p1; p += 2) {
            int sn = esrc[p + half];
            half8 hv = *(const half8*)&Hin[(size_t)sn * F + j * 8];
            float wgt = __expf(fminf(lrelu(Sin[sn * 8 + hh] + sdst), 60.f));
            d += wgt;
            a0 = fmaf(wgt, (float)hv[0], a0);
            a1 = fmaf(wgt, (float)hv[1], a1);
            a2 = fmaf(wgt, (float)hv[2], a2);
            a3 = fmaf(wgt, (float)hv[3], a3);
            a4 = fmaf(wgt, (float)hv[4], a4);
            a5 = fmaf(wgt, (float)hv[5], a5);
            a6 = fmaf(wgt, (float)hv[6], a6);
            a7 = fmaf(wgt, (float)hv[7], a7);
        }
        if (p < p1) {                                // odd tail: half==1 lanes contribute 0
            int sn = esrc[p];
            half8 hv = *(const half8*)&Hin[(size_t)sn * F + j * 8];
            float wgt = (half == 0) ? __expf(fminf(lrelu(Sin[sn * 8 + hh] + sdst), 60.f)) : 0.f;
            d += wgt;
            a0 = fmaf(wgt, (float)hv[0], a0);
            a1 = fmaf(wgt, (float)hv[1], a1);
            a2 = fmaf(wgt, (float)hv[2], a2);
            a3 = fmaf(wgt, (float)hv[3], a3);
            a4 = fmaf(wgt, (float)hv[4], a4);
            a5 = fmaf(wgt, (float)hv[5], a5);
            a6 = fmaf(wgt, (float)hv[6], a6);
            a7 = fmaf(wgt, (float)hv[7], a7);
        }

        d  += __shfl_xor(d, 32, 64);
        a0 += __shfl_xor(a0, 32, 64);
        a1 += __shfl_xor(a1, 32, 64);
        a2 += __shfl_xor(a2, 32, 64);
        a3 += __shfl_xor(a3, 32, 64);
        a4 += __shfl_xor(a4, 32, 64);
        a5 += __shfl_xor(a5, 32, 64);
        a6 += __shfl_xor(a6, 32, 64);
        a7 += __shfl_xor(a7, 32, 64);

        float inv = 1.f / d;
        if (half == 0) {
            half8 o;
            o[0] = (_Float16)fmaxf(fmaf(a0, inv, ba.x), 0.f);
            o[1] = (_Float16)fmaxf(fmaf(a1, inv, ba.y), 0.f);
            o[2] = (_Float16)fmaxf(fmaf(a2, inv, ba.z), 0.f);
            o[3] = (_Float16)fmaxf(fmaf(a3, inv, ba.w), 0.f);
            o[4] = (_Float16)fmaxf(fmaf(a4, inv, bb2.x), 0.f);
            o[5] = (_Float16)fmaxf(fmaf(a5, inv, bb2.y), 0.f);
            o[6] = (_Float16)fmaxf(fmaf(a6, inv, bb2.z), 0.f);
            o[7] = (_Float16)fmaxf(fmaf(a7, inv, bb2.w), 0.f);
            *(half8*)&xs[w * 2 + r][j * 8] = o;
        }
    }
    __syncthreads();

    // ---- gemm phase: wave = (head, col-half) 16x32 sub-tile, A from LDS ----
    int head = w >> 1, ch = w & 1;
    int lr = l & 15, lg = l >> 4;
    int col0 = head * 64 + ch * 32;

    int offB[2];
    #pragma unroll
    for (int n = 0; n < 2; n++) offB[n] = (col0 + n * 16 + lr) * F + lg * 8;

    half8 aa[2], bbf[2][2];
    aa[0] = *(const half8*)&xs[lr][lg * 8];
    #pragma unroll
    for (int n = 0; n < 2; n++) bbf[0][n] = *(const half8*)&Wt[offB[n]];

    f4 acc[2] = {};
    #pragma unroll
    for (int it = 0; it < 8; it++) {
        const int cur = it & 1, nxt = cur ^ 1;
        if (it < 7) {
            int k0 = (it + 1) * 32;
            aa[nxt] = *(const half8*)&xs[lr][lg * 8 + k0];
            #pragma unroll
            for (int n = 0; n < 2; n++) bbf[nxt][n] = *(const half8*)&Wt[offB[n] + k0];
        }
        #pragma unroll
        for (int n = 0; n < 2; n++)
            acc[n] = __builtin_amdgcn_mfma_f32_16x16x32_f16(aa[cur], bbf[cur][n], acc[n], 0, 0, 0);
    }

    float as_r[2], ad_r[2];
    #pragma unroll
    for (int n = 0; n < 2; n++) {
        as_r[n] = As[head * 64 + ch * 32 + n * 16 + lr];
        ad_r[n] = Ad[head * 64 + ch * 32 + n * 16 + lr];
    }

    #pragma unroll
    for (int j2 = 0; j2 < 4; j2++) {
        int rr = row0 + lg * 4 + j2;
        float ssum = 0.f, dsum = 0.f;
        #pragma unroll
        for (int n = 0; n < 2; n++) {
            float v = acc[n][j2];
            Hout[(size_t)rr * F + col0 + n * 16 + lr] = (_Float16)v;
            ssum = fmaf(v, as_r[n], ssum);
            dsum = fmaf(v, ad_r[n], dsum);
        }
        #pragma unroll
        for (int o = 1; o < 16; o <<= 1) {
            ssum += __shfl_xor(ssum, o, 64);
            dsum += __shfl_xor(dsum, o, 64);
        }
        if (lr == 0) {
            sm_s[w][lg * 4 + j2] = ssum;
            sm_d[w][lg * 4 + j2] = dsum;
        }
    }
    __syncthreads();

    // combine the two col-halves of each head; waves 0-3 = heads, lane < 16 = row
    if (w < 4 && l < 16) {
        int rr = row0 + l;
        Sout[rr * 8 + w]     = sm_s[2 * w][l] + sm_s[2 * w + 1][l];
        Sout[rr * 8 + 4 + w] = sm_d[2 * w][l] + sm_d[2 * w + 1][l];
    }
}

// ---------------- final softmax aggregation + bias + L2-normalize ----------------
__global__ __launch_bounds__(256) void k_aggF(const _Float16* __restrict__ Hm, const float* __restrict__ S,
                                              const int* __restrict__ offs, const int* __restrict__ esrc,
                                              const float* __restrict__ bias,
                                              float* __restrict__ ofp) {
    int node = blockIdx.x * 4 + (threadIdx.x >> 6);
    if (node >= NN) return;
    int l = threadIdx.x & 63;
    int half = l >> 5;
    int j = l & 31;
    int hh = j >> 3;

    int p0 = offs[node], p1 = offs[node + 1];
    float sdst = S[node * 8 + 4 + hh];

    float a0 = 0.f, a1 = 0.f, a2 = 0.f, a3 = 0.f;
    float a4 = 0.f, a5 = 0.f, a6 = 0.f, a7 = 0.f;
    float d = 0.f;
    int p = p0;
    for (; p + 8 <= p1; p += 8) {
        int sn[4];
        #pragma unroll
        for (int i = 0; i < 4; i++) sn[i] = esrc[p + 2 * i + half];
        half8 hv[4];
        #pragma unroll
        for (int i = 0; i < 4; i++) hv[i] = *(const half8*)&Hm[(size_t)sn[i] * F + j * 8];
        float wgt[4];
        #pragma unroll
        for (int i = 0; i < 4; i++)
            wgt[i] = __expf(fminf(lrelu(S[sn[i] * 8 + hh] + sdst), 60.f));
        #pragma unroll
        for (int i = 0; i < 4; i++) {
            d += wgt[i];
            a0 = fmaf(wgt[i], (float)hv[i][0], a0);
            a1 = fmaf(wgt[i], (float)hv[i][1], a1);
            a2 = fmaf(wgt[i], (float)hv[i][2], a2);
            a3 = fmaf(wgt[i], (float)hv[i][3], a3);
            a4 = fmaf(wgt[i], (float)hv[i][4], a4);
            a5 = fmaf(wgt[i], (float)hv[i][5], a5);
            a6 = fmaf(wgt[i], (float)hv[i][6], a6);
            a7 = fmaf(wgt[i], (float)hv[i][7], a7);
        }
    }
    for (; p + 2 <= p1; p += 2) {
        int sn = esrc[p + half];
        half8 hv = *(const half8*)&Hm[(size_t)sn * F + j * 8];
        float wgt = __expf(fminf(lrelu(S[sn * 8 + hh] + sdst), 60.f));
        d += wgt;
        a0 = fmaf(wgt, (float)hv[0], a0);
        a1 = fmaf(wgt, (float)hv[1], a1);
        a2 = fmaf(wgt, (float)hv[2], a2);
        a3 = fmaf(wgt, (float)hv[3], a3);
        a4 = fmaf(wgt, (float)hv[4], a4);
        a5 = fmaf(wgt, (float)hv[5], a5);
        a6 = fmaf(wgt, (float)hv[6], a6);
        a7 = fmaf(wgt, (float)hv[7], a7);
    }
    if (p < p1) {
        int sn = esrc[p];
        half8 hv = *(const half8*)&Hm[(size_t)sn * F + j * 8];
        float wgt = (half == 0) ? __expf(fminf(lrelu(S[sn * 8 + hh] + sdst), 60.f)) : 0.f;
        d += wgt;
        a0 = fmaf(wgt, (float)hv[0], a0);
        a1 = fmaf(wgt, (float)hv[1], a1);
        a2 = fmaf(wgt, (float)hv[2], a2);
        a3 = fmaf(wgt, (float)hv[3], a3);
        a4 = fmaf(wgt, (float)hv[4], a4);
        a5 = fmaf(wgt, (float)hv[5], a5);
        a6 = fmaf(wgt, (float)hv[6], a6);
        a7 = fmaf(wgt, (float)hv[7], a7);
    }

    d  += __shfl_xor(d, 32, 64);
    a0 += __shfl_xor(a0, 32, 64);
    a1 += __shfl_xor(a1, 32, 64);
    a2 += __shfl_xor(a2, 32, 64);
    a3 += __shfl_xor(a3, 32, 64);
    a4 += __shfl_xor(a4, 32, 64);
    a5 += __shfl_xor(a5, 32, 64);
    a6 += __shfl_xor(a6, 32, 64);
    a7 += __shfl_xor(a7, 32, 64);

    float inv = 1.f / d;
    float4 ba = ((const float4*)bias)[2 * j];
    float4 bb = ((const float4*)bias)[2 * j + 1];
    float r0 = fmaf(a0, inv, ba.x);
    float r1 = fmaf(a1, inv, ba.y);
    float r2 = fmaf(a2, inv, ba.z);
    float r3 = fmaf(a3, inv, ba.w);
    float r4 = fmaf(a4, inv, bb.x);
    float r5 = fmaf(a5, inv, bb.y);
    float r6 = fmaf(a6, inv, bb.z);
    float r7 = fmaf(a7, inv, bb.w);

    float ss = r0 * r0 + r1 * r1 + r2 * r2 + r3 * r3
             + r4 * r4 + r5 * r5 + r6 * r6 + r7 * r7;
    #pragma unroll
    for (int o = 1; o < 32; o <<= 1) ss += __shfl_xor(ss, o, 64);
    float nrm = 1.f / fmaxf(sqrtf(ss), 1e-12f);
    if (half == 0) {
        ((float4*)ofp)[(size_t)node * 64 + 2 * j] =
            make_float4(r0 * nrm, r1 * nrm, r2 * nrm, r3 * nrm);
        ((float4*)ofp)[(size_t)node * 64 + 2 * j + 1] =
            make_float4(r4 * nrm, r5 * nrm, r6 * nrm, r7 * nrm);
    }
}

extern "C" void kernel_launch(void* const* d_in, const int* in_sizes, int n_in,
                              void* d_out, int out_size, void* d_ws, size_t ws_size,
                              hipStream_t stream) {
    const float* x = (const float*)d_in[0];
    const int* ei = (const int*)d_in[1];
    const int* src = ei;            // edge_index[0]
    const int* dst = ei + NE;       // edge_index[1]
    const float* W[3]  = {(const float*)d_in[2],  (const float*)d_in[6],  (const float*)d_in[10]};
    const float* As[3] = {(const float*)d_in[3],  (const float*)d_in[7],  (const float*)d_in[11]};
    const float* Ad[3] = {(const float*)d_in[4],  (const float*)d_in[8],  (const float*)d_in[12]};
    const float* Bs[3] = {(const float*)d_in[5],  (const float*)d_in[9],  (const float*)d_in[13]};
    float* out = (float*)d_out;

    // workspace carve (all 16B aligned); H/S double-buffered across layers
    char* w = (char*)d_ws;
    _Float16* H_A = (_Float16*)w;            w += (size_t)NN * F * 2;        // 10.24 MB
    _Float16* H_B = (_Float16*)w;            w += (size_t)NN * F * 2;        // 10.24 MB
    float* S_A = (float*)w;                  w += (size_t)NN * 8 * 4;        // 0.64 MB
    float* S_B = (float*)w;                  w += (size_t)NN * 8 * 4;        // 0.64 MB
    _Float16* Wt = (_Float16*)w;             w += (size_t)3 * F * F * 2;     // 0.39 MB
    int* counts = (int*)w;                   w += (size_t)NN * 4;            // cursor after scan
    int* offs = (int*)w;                     w += (size_t)(NN + 4) * 4;
    int* bsum = (int*)w;                     w += (size_t)32 * 4;
    int* esrc = (int*)w;

    hipMemsetAsync(counts, 0, (size_t)NN * 4, stream);
    k_prep<<<PREP_B, 256, 0, stream>>>(W[0], W[1], W[2], dst, Wt, counts);
    k_scanA<<<SCAN_B, 1024, 0, stream>>>(counts, offs, bsum);
    k_scanB<<<SCAN_B, 1024, 0, stream>>>(offs, bsum, esrc, counts);

    // layer 1 gemm (+edge fill) -> H_A,S_A
    k_gemm1<<<GTILES + FILL_B, 256, 0, stream>>>(x, Wt, As[0], Ad[0], H_A, S_A,
                                                 src, dst, counts, esrc);
    // agg1 + gemm2 -> H_B,S_B
    k_aggemm<<<AGTILES, 512, 0, stream>>>(H_A, S_A, offs, esrc, Bs[0],
                                          Wt + 65536, As[1], Ad[1], H_B, S_B);
    // agg2 + gemm3 -> H_A,S_A
    k_aggemm<<<AGTILES, 512, 0, stream>>>(H_B, S_B, offs, esrc, Bs[1],
                                          Wt + 2 * 65536, As[2], Ad[2], H_A, S_A);
    // agg3 + bias + L2-normalize -> out
    k_aggF<<<(NN + 3) / 4, 256, 0, stream>>>(H_A, S_A, offs, esrc, Bs[2], out);
}